// Round 3
// baseline (449.520 us; speedup 1.0000x reference)
//
#include <hip/hip_runtime.h>
#include <hip/hip_fp16.h>

// CommNet critic forward, fused: 1 WG (256 thr, 4 waves) = 1 batch (32 agents).
// GEMMs via v_mfma_f32_16x16x32_f16 (fp32 acc). B=2048, A=32, D=128, H=256.
// R3: fix R2's register spill (WRITE_SIZE 495 MB of scratch):
//   - __launch_bounds__(256,3): reg cap ~170 fits the ~160-reg footprint; 3 blocks/CU
//   - USE_PREP as template param: dead fallback path removed from hot kernel

#define NB   2048
#define NA   32
#define DIN  128
#define HID  256
#define SA   264   // f16 row stride for activation LDS tiles

typedef _Float16 half8  __attribute__((ext_vector_type(8)));
typedef _Float16 half4_t __attribute__((ext_vector_type(4)));
typedef float    float4v __attribute__((ext_vector_type(4)));

// f16 weight-fragment arena in d_ws (element offsets)
#define ENC_OFF    0
#define FOBS_OFF   32768
#define WIH_OFF    98304
#define WHH_OFF    294912
#define PREP_TOTAL 491520   // f16 elements -> 983040 bytes

// One wave per (matrix, ks, nt) fragment tile: reads a 16-row x 32-k fp32 block
// (2x float4 per lane), writes one coalesced half8 per lane.
// frag[((ks*NT + nt)*64 + lane)*8 + j] = W[nt*16 + lane%16][ks*32 + (lane/16)*8 + j]
__global__ __launch_bounds__(256) void prep_weights(
        const float* __restrict__ encW, const float* __restrict__ fobsW,
        const float* __restrict__ wih,  const float* __restrict__ whh,
        _Float16* __restrict__ prep) {
    int W = blockIdx.x * 4 + (threadIdx.x >> 6);   // global wave id, 0..959
    int lane = threadIdx.x & 63;
    const float* src; int K, NT, base, idx;
    if (W < 64)       { src = encW;  K = 128; NT = 16; base = ENC_OFF;  idx = W; }
    else if (W < 192) { src = fobsW; K = 256; NT = 16; base = FOBS_OFF; idx = W - 64; }
    else if (W < 576) { src = wih;   K = 256; NT = 48; base = WIH_OFF;  idx = W - 192; }
    else              { src = whh;   K = 256; NT = 48; base = WHH_OFF;  idx = W - 576; }
    int nt = idx % NT, ks = idx / NT;
    int l16 = lane & 15, q = lane >> 4;
    const float* s = src + (size_t)(nt * 16 + l16) * K + ks * 32 + q * 8;
    float4v f0 = *(const float4v*)s;
    float4v f1 = *(const float4v*)(s + 4);
    half8 h;
    h[0] = (_Float16)f0[0]; h[1] = (_Float16)f0[1]; h[2] = (_Float16)f0[2]; h[3] = (_Float16)f0[3];
    h[4] = (_Float16)f1[0]; h[5] = (_Float16)f1[1]; h[6] = (_Float16)f1[2]; h[7] = (_Float16)f1[3];
    *(half8*)(prep + base + (((size_t)(ks * NT + nt) * 64 + lane) << 3)) = h;
}

__device__ __forceinline__ float sigmoid_f(float x) {
    x = fminf(fmaxf(x, -30.f), 30.f);
    return 1.f / (1.f + __expf(-x));
}
__device__ __forceinline__ float tanh_f(float x) {
    x = fminf(fmaxf(x, -15.f), 15.f);
    float e = __expf(-2.f * x);
    return (1.f - e) / (1.f + e);
}

__device__ __forceinline__ void zero24(float4v a[2][4]) {
    float4v z = {0.f, 0.f, 0.f, 0.f};
    #pragma unroll
    for (int m = 0; m < 2; m++)
        #pragma unroll
        for (int n = 0; n < 4; n++) a[m][n] = z;
}

// One wave: [32 rows] x [4 ntiles = 64 cols]. A from LDS (stride SA), B from
// prepped fragments (global, L2-resident) or raw fp32 fallback.
template<int KSTEPS, int USE_PREP>
__device__ __forceinline__ void gemm_tile4(const _Float16* __restrict__ Abuf,
        const _Float16* __restrict__ prepm, int NT, int ntg0,
        const float* __restrict__ raw, int K,
        int lane, float4v acc[2][4])
{
    const int l16 = lane & 15;
    const int kq  = (lane >> 4) << 3;
    #pragma unroll
    for (int ks = 0; ks < KSTEPS; ks++) {
        int kbase = ks * 32 + kq;
        half8 a0 = *(const half8*)(Abuf + l16 * SA + kbase);
        half8 a1 = *(const half8*)(Abuf + (16 + l16) * SA + kbase);
        #pragma unroll
        for (int nn = 0; nn < 4; nn++) {
            half8 b;
            if (USE_PREP) {
                b = *(const half8*)(prepm + (((ks * NT + ntg0 + nn) * 64 + lane) << 3));
            } else {
                #pragma unroll
                for (int j = 0; j < 8; j++)
                    b[j] = (_Float16)raw[((ntg0 + nn) * 16 + l16) * K + kbase + j];
            }
            acc[0][nn] = __builtin_amdgcn_mfma_f32_16x16x32_f16(a0, b, acc[0][nn], 0, 0, 0);
            acc[1][nn] = __builtin_amdgcn_mfma_f32_16x16x32_f16(a1, b, acc[1][nn], 0, 0, 0);
        }
    }
}

template<int USE_PREP>
__global__ __launch_bounds__(256, 3) void commnet_fused(
    const float* __restrict__ obs, const _Float16* __restrict__ prep,
    const float* __restrict__ enc_b, const float* __restrict__ fobs_b,
    const float* __restrict__ b_ih, const float* __restrict__ b_hh,
    const float* __restrict__ dec_W, const float* __restrict__ dec_b,
    float* __restrict__ out,
    const float* __restrict__ encW, const float* __restrict__ fobsW,
    const float* __restrict__ wih, const float* __restrict__ whh)
{
    const int b    = blockIdx.x;
    const int tid  = threadIdx.x;
    const int lane = tid & 63;
    const int w    = tid >> 6;     // wave 0..3
    const int l16  = lane & 15;
    const int quad = lane >> 4;
    const int ntl0 = w * 4;        // this wave's 4 ntiles within 16 (256 cols)

    __shared__ __align__(16) _Float16 sA[2][NA * SA];
    __shared__ float S[HID];
    __shared__ float D[NA];

    // ---- stage obs (fp32 -> f16 LDS sA[0]); zero S, D
    const float* obsb = obs + (size_t)b * NA * DIN;
    #pragma unroll
    for (int j = 0; j < 4; j++) {
        int i = tid + j * 256;             // float4 index, 1024 total
        float4v v = ((const float4v*)obsb)[i];
        int r = i >> 5, kd = (i & 31) * 4;
        half4_t hv;
        hv[0] = (_Float16)v[0]; hv[1] = (_Float16)v[1];
        hv[2] = (_Float16)v[2]; hv[3] = (_Float16)v[3];
        *(half4_t*)(&sA[0][r * SA + kd]) = hv;
    }
    if (tid < HID) S[tid] = 0.f;
    if (tid < NA)  D[tid] = 0.f;
    __syncthreads();

    float4v acc[2][4];
    float rn[2][4][4];

    // ---- encoder: e = relu(obs @ encW^T + enc_b) -> sA[1]
    zero24(acc);
    gemm_tile4<4, USE_PREP>(&sA[0][0], prep + ENC_OFF, 16, ntl0, encW, DIN, lane, acc);
    #pragma unroll
    for (int nn = 0; nn < 4; nn++) {
        int col = (ntl0 + nn) * 16 + l16;
        float bb = enc_b[col];
        #pragma unroll
        for (int mt = 0; mt < 2; mt++)
            #pragma unroll
            for (int r = 0; r < 4; r++) {
                int row = mt * 16 + quad * 4 + r;
                sA[1][row * SA + col] = (_Float16)fmaxf(acc[mt][nn][r] + bb, 0.f);
            }
    }
    __syncthreads();

    // ---- fobs: h = e @ fobsW^T + fobs_b -> sA[0] (obs dead)
    zero24(acc);
    gemm_tile4<8, USE_PREP>(&sA[1][0], prep + FOBS_OFF, 16, ntl0, fobsW, HID, lane, acc);
    #pragma unroll
    for (int nn = 0; nn < 4; nn++) {
        int col = (ntl0 + nn) * 16 + l16;
        float bb = fobs_b[col];
        #pragma unroll
        for (int mt = 0; mt < 2; mt++)
            #pragma unroll
            for (int r = 0; r < 4; r++) {
                int row = mt * 16 + quad * 4 + r;
                sA[0][row * SA + col] = (_Float16)(acc[mt][nn][r] + bb);
            }
    }
    __syncthreads();

    // ---- GRU1 (x=0 => gi = b_ih). A = sA[0] (h). gate ntile bases: r=0, z=16, n=32
    zero24(acc);
    gemm_tile4<8, USE_PREP>(&sA[0][0], prep + WHH_OFF, 48, 0 + ntl0, whh, HID, lane, acc);
    #pragma unroll
    for (int nn = 0; nn < 4; nn++) {
        int col = (ntl0 + nn) * 16 + l16;
        float bi = b_ih[col], bh = b_hh[col];
        #pragma unroll
        for (int mt = 0; mt < 2; mt++)
            #pragma unroll
            for (int r = 0; r < 4; r++)
                rn[mt][nn][r] = sigmoid_f(bi + acc[mt][nn][r] + bh);   // r-gate
    }
    zero24(acc);
    gemm_tile4<8, USE_PREP>(&sA[0][0], prep + WHH_OFF, 48, 32 + ntl0, whh, HID, lane, acc);
    #pragma unroll
    for (int nn = 0; nn < 4; nn++) {
        int col = (ntl0 + nn) * 16 + l16;
        float bi = b_ih[512 + col], bh = b_hh[512 + col];
        #pragma unroll
        for (int mt = 0; mt < 2; mt++)
            #pragma unroll
            for (int r = 0; r < 4; r++)
                rn[mt][nn][r] = tanh_f(bi + rn[mt][nn][r] * (acc[mt][nn][r] + bh));  // n-gate
    }
    zero24(acc);
    gemm_tile4<8, USE_PREP>(&sA[0][0], prep + WHH_OFF, 48, 16 + ntl0, whh, HID, lane, acc);
    #pragma unroll
    for (int nn = 0; nn < 4; nn++) {
        int col = (ntl0 + nn) * 16 + l16;
        float bi = b_ih[256 + col], bh = b_hh[256 + col];
        float ssum = 0.f;
        #pragma unroll
        for (int mt = 0; mt < 2; mt++)
            #pragma unroll
            for (int r = 0; r < 4; r++) {
                int row = mt * 16 + quad * 4 + r;
                float z = sigmoid_f(bi + acc[mt][nn][r] + bh);
                float hold = (float)sA[0][row * SA + col];
                float h1 = (1.f - z) * rn[mt][nn][r] + z * hold;
                sA[1][row * SA + col] = (_Float16)h1;   // h1 -> sA[1] (e dead)
                ssum += h1;
            }
        atomicAdd(&S[col], ssum);                       // column sums for comm
    }
    __syncthreads();

    // ---- comm: c = (S - h1)/32 -> sA[0] (h dead)
    #pragma unroll
    for (int j = 0; j < 8; j++) {
        int i = tid + j * 256;             // half4 groups, 2048 total
        int r = i >> 6, cg = (i & 63) * 4;
        half4_t hv = *(const half4_t*)(&sA[1][r * SA + cg]);
        half4_t cv;
        #pragma unroll
        for (int t = 0; t < 4; t++)
            cv[t] = (_Float16)((S[cg + t] - (float)hv[t]) * (1.f / 32.f));
        *(half4_t*)(&sA[0][r * SA + cg]) = cv;
    }
    __syncthreads();

    // ---- GRU2: gi = c @ W_ih, gh = h1 @ W_hh; r/z gates chain both into one acc
    zero24(acc);
    gemm_tile4<8, USE_PREP>(&sA[0][0], prep + WIH_OFF, 48, 0 + ntl0, wih, HID, lane, acc);
    gemm_tile4<8, USE_PREP>(&sA[1][0], prep + WHH_OFF, 48, 0 + ntl0, whh, HID, lane, acc);
    #pragma unroll
    for (int nn = 0; nn < 4; nn++) {
        int col = (ntl0 + nn) * 16 + l16;
        float bb = b_ih[col] + b_hh[col];
        #pragma unroll
        for (int mt = 0; mt < 2; mt++)
            #pragma unroll
            for (int r = 0; r < 4; r++)
                rn[mt][nn][r] = sigmoid_f(acc[mt][nn][r] + bb);       // r-gate
    }
    zero24(acc);
    gemm_tile4<8, USE_PREP>(&sA[1][0], prep + WHH_OFF, 48, 32 + ntl0, whh, HID, lane, acc);
    #pragma unroll
    for (int nn = 0; nn < 4; nn++) {
        int col = (ntl0 + nn) * 16 + l16;
        float bh = b_hh[512 + col];
        #pragma unroll
        for (int mt = 0; mt < 2; mt++)
            #pragma unroll
            for (int r = 0; r < 4; r++)
                rn[mt][nn][r] = rn[mt][nn][r] * (acc[mt][nn][r] + bh); // r * (h_n)
    }
    zero24(acc);
    gemm_tile4<8, USE_PREP>(&sA[0][0], prep + WIH_OFF, 48, 32 + ntl0, wih, HID, lane, acc);
    #pragma unroll
    for (int nn = 0; nn < 4; nn++) {
        int col = (ntl0 + nn) * 16 + l16;
        float bi = b_ih[512 + col];
        #pragma unroll
        for (int mt = 0; mt < 2; mt++)
            #pragma unroll
            for (int r = 0; r < 4; r++)
                rn[mt][nn][r] = tanh_f(acc[mt][nn][r] + bi + rn[mt][nn][r]);  // n-gate
    }
    zero24(acc);
    gemm_tile4<8, USE_PREP>(&sA[0][0], prep + WIH_OFF, 48, 16 + ntl0, wih, HID, lane, acc);
    gemm_tile4<8, USE_PREP>(&sA[1][0], prep + WHH_OFF, 48, 16 + ntl0, whh, HID, lane, acc);
    float dw[4];
    #pragma unroll
    for (int nn = 0; nn < 4; nn++) dw[nn] = dec_W[(ntl0 + nn) * 16 + l16];
    float p[2][4] = {};
    #pragma unroll
    for (int nn = 0; nn < 4; nn++) {
        int col = (ntl0 + nn) * 16 + l16;
        float bb = b_ih[256 + col] + b_hh[256 + col];
        #pragma unroll
        for (int mt = 0; mt < 2; mt++)
            #pragma unroll
            for (int r = 0; r < 4; r++) {
                int row = mt * 16 + quad * 4 + r;
                float z = sigmoid_f(acc[mt][nn][r] + bb);
                float h1v = (float)sA[1][row * SA + col];
                float h2 = (1.f - z) * rn[mt][nn][r] + z * h1v;
                p[mt][r] += h2 * dw[nn];               // fuse decoder dot
            }
    }

    // ---- decoder reduce: sum over cols (l16 lanes) then across waves via LDS
    #pragma unroll
    for (int m = 1; m <= 8; m <<= 1)
        #pragma unroll
        for (int mt = 0; mt < 2; mt++)
            #pragma unroll
            for (int r = 0; r < 4; r++)
                p[mt][r] += __shfl_xor(p[mt][r], m);
    if (l16 == 0) {
        #pragma unroll
        for (int mt = 0; mt < 2; mt++)
            #pragma unroll
            for (int r = 0; r < 4; r++)
                atomicAdd(&D[mt * 16 + quad * 4 + r], p[mt][r]);
    }
    __syncthreads();
    if (tid < NA) out[(size_t)b * NA + tid] = D[tid] + dec_b[0];
}

extern "C" void kernel_launch(void* const* d_in, const int* in_sizes, int n_in,
                              void* d_out, int out_size, void* d_ws, size_t ws_size,
                              hipStream_t stream) {
    const float* obs   = (const float*)d_in[0];
    // d_in[1] (act) unused by reference
    const float* encW  = (const float*)d_in[2];
    const float* encb  = (const float*)d_in[3];
    const float* fobsW = (const float*)d_in[4];
    const float* fobsb = (const float*)d_in[5];
    const float* wih   = (const float*)d_in[6];
    const float* bih   = (const float*)d_in[7];
    const float* whh   = (const float*)d_in[8];
    const float* bhh   = (const float*)d_in[9];
    const float* decW  = (const float*)d_in[10];
    const float* decb  = (const float*)d_in[11];
    float* out = (float*)d_out;

    _Float16* prep = (_Float16*)d_ws;
    if (ws_size >= (size_t)PREP_TOTAL * sizeof(_Float16)) {
        prep_weights<<<240, 256, 0, stream>>>(encW, fobsW, wih, whh, prep);
        commnet_fused<1><<<NB, 256, 0, stream>>>(obs, prep, encb, fobsb, bih, bhh,
                                                 decW, decb, out, encW, fobsW, wih, whh);
    } else {
        commnet_fused<0><<<NB, 256, 0, stream>>>(obs, prep, encb, fobsb, bih, bhh,
                                                 decW, decb, out, encW, fobsW, wih, whh);
    }
}

// Round 4
// 403.911 us; speedup vs baseline: 1.1129x; 1.1129x over previous
//
#include <hip/hip_runtime.h>
#include <hip/hip_fp16.h>

// CommNet critic forward. R4: wave-private restructure.
// 1 WG = 128 thr = 2 waves = 1 batch (32 agents); each wave owns 16 rows and
// runs enc->fobs->GRU1->GRU2 entirely on its private LDS ping-pong tiles.
// Exactly ONE __syncthreads (cross-agent mean). M=16 MFMA tiles, N in 4-ntile
// chunks. launch_bounds(128,2) -> 256-reg cap, unroll-2 k-loops -> no spill.

#define NB   2048
#define NA   32
#define DIN  128
#define HID  256
#define SA   264   // f16 row stride (132 words: lane row*4 mod 32 -> 2-way max, free)

typedef _Float16 half8   __attribute__((ext_vector_type(8)));
typedef _Float16 half4_t __attribute__((ext_vector_type(4)));
typedef float    float4v __attribute__((ext_vector_type(4)));

// f16 weight-fragment arena in d_ws (element offsets)
#define ENC_OFF    0
#define FOBS_OFF   32768
#define WIH_OFF    98304
#define WHH_OFF    294912
#define PREP_TOTAL 491520   // f16 elements -> 983040 bytes

// One wave per (matrix, ks, nt) fragment tile; coalesced f32x4 reads, half8 write.
// frag[((ks*NT + nt)*64 + lane)*8 + j] = W[nt*16 + lane%16][ks*32 + (lane/16)*8 + j]
__global__ __launch_bounds__(256) void prep_weights(
        const float* __restrict__ encW, const float* __restrict__ fobsW,
        const float* __restrict__ wih,  const float* __restrict__ whh,
        _Float16* __restrict__ prep) {
    int W = blockIdx.x * 4 + (threadIdx.x >> 6);   // wave id 0..959
    int lane = threadIdx.x & 63;
    const float* src; int K, NT, base, idx;
    if (W < 64)       { src = encW;  K = 128; NT = 16; base = ENC_OFF;  idx = W; }
    else if (W < 192) { src = fobsW; K = 256; NT = 16; base = FOBS_OFF; idx = W - 64; }
    else if (W < 576) { src = wih;   K = 256; NT = 48; base = WIH_OFF;  idx = W - 192; }
    else              { src = whh;   K = 256; NT = 48; base = WHH_OFF;  idx = W - 576; }
    int nt = idx % NT, ks = idx / NT;
    int l16 = lane & 15, q = lane >> 4;
    const float* s = src + (size_t)(nt * 16 + l16) * K + ks * 32 + q * 8;
    float4v f0 = *(const float4v*)s;
    float4v f1 = *(const float4v*)(s + 4);
    half8 h;
    h[0] = (_Float16)f0[0]; h[1] = (_Float16)f0[1]; h[2] = (_Float16)f0[2]; h[3] = (_Float16)f0[3];
    h[4] = (_Float16)f1[0]; h[5] = (_Float16)f1[1]; h[6] = (_Float16)f1[2]; h[7] = (_Float16)f1[3];
    *(half8*)(prep + base + (((size_t)(ks * NT + nt) * 64 + lane) << 3)) = h;
}

__device__ __forceinline__ float sigmoid_f(float x) {
    x = fminf(fmaxf(x, -30.f), 30.f);
    return 1.f / (1.f + __expf(-x));
}
__device__ __forceinline__ float tanh_f(float x) {
    x = fminf(fmaxf(x, -15.f), 15.f);
    float e = __expf(-2.f * x);
    return (1.f - e) / (1.f + e);
}
__device__ __forceinline__ void zero4(float4v a[4]) {
    float4v z = {0.f, 0.f, 0.f, 0.f};
    a[0] = z; a[1] = z; a[2] = z; a[3] = z;
}

// One wave: 16 rows x 64 cols (4 ntiles). Ab pre-offset = Abuf + l16*SA + kq.
// Bp pre-offset = prep + base + gnt0*512 + lane*8; stride ldbk = NT*512 per ks.
// rawp pre-offset = rawW + (gnt0*16 + l16)*K + kq (fallback path).
template<int KSTEPS, int USE_PREP>
__device__ __forceinline__ void gemm_chunk4(
        const _Float16* __restrict__ Ab,
        const _Float16* __restrict__ Bp, int ldbk,
        const float* __restrict__ rawp, int K,
        float4v acc[4])
{
    #pragma unroll 2
    for (int ks = 0; ks < KSTEPS; ks++) {
        half8 a = *(const half8*)(Ab + ks * 32);
        #pragma unroll
        for (int nn = 0; nn < 4; nn++) {
            half8 b;
            if (USE_PREP) {
                b = *(const half8*)(Bp + ks * ldbk + nn * 512);
            } else {
                #pragma unroll
                for (int j = 0; j < 8; j++)
                    b[j] = (_Float16)rawp[(size_t)nn * 16 * K + ks * 32 + j];
            }
            acc[nn] = __builtin_amdgcn_mfma_f32_16x16x32_f16(a, b, acc[nn], 0, 0, 0);
        }
    }
}

template<int USE_PREP>
__global__ __launch_bounds__(128, 2) void commnet_fused(
    const float* __restrict__ obs, const _Float16* __restrict__ prep,
    const float* __restrict__ enc_b, const float* __restrict__ fobs_b,
    const float* __restrict__ b_ih, const float* __restrict__ b_hh,
    const float* __restrict__ dec_W, const float* __restrict__ dec_b,
    float* __restrict__ out,
    const float* __restrict__ encW, const float* __restrict__ fobsW,
    const float* __restrict__ wih, const float* __restrict__ whh)
{
    const int b    = blockIdx.x;
    const int tid  = threadIdx.x;
    const int lane = tid & 63;
    const int wv   = tid >> 6;      // wave 0/1 -> agent rows wv*16..wv*16+15
    const int l16  = lane & 15;
    const int quad = lane >> 4;
    const int kq   = quad << 3;
    const int lane8 = lane << 3;

    __shared__ __align__(16) _Float16 buf[2][2][16 * SA];  // [wave][pingpong]
    __shared__ __align__(16) float Sp[2][HID];             // per-wave colsums

    _Float16* b0 = &buf[wv][0][0];
    _Float16* b1 = &buf[wv][1][0];
    const _Float16* Ab0 = b0 + l16 * SA + kq;
    const _Float16* Ab1 = b1 + l16 * SA + kq;

    // ---- stage this wave's 16x128 obs rows (fp32 -> f16 LDS b0); no barrier
    {
        const float* obsw = obs + ((size_t)b * NA + wv * 16) * DIN;
        #pragma unroll
        for (int it = 0; it < 8; it++) {
            int i = it * 64 + lane;            // float4 idx, 512 total
            float4v v = ((const float4v*)obsw)[i];
            int row = i >> 5, c4 = (i & 31) * 4;
            half4_t hv;
            hv[0] = (_Float16)v[0]; hv[1] = (_Float16)v[1];
            hv[2] = (_Float16)v[2]; hv[3] = (_Float16)v[3];
            *(half4_t*)(b0 + row * SA + c4) = hv;
        }
    }

    float4v acc[4];

    // ---- encoder: e = relu(obs @ encW^T + b) : b0 -> b1
    #pragma unroll 1
    for (int ch = 0; ch < 4; ch++) {
        zero4(acc);
        gemm_chunk4<4, USE_PREP>(Ab0, prep + ENC_OFF + (ch * 4) * 512 + lane8, 16 * 512,
                                 encW + (size_t)(ch * 64 + l16) * DIN + kq, DIN, acc);
        #pragma unroll
        for (int nn = 0; nn < 4; nn++) {
            int col = ch * 64 + nn * 16 + l16;
            float bb = enc_b[col];
            #pragma unroll
            for (int rr = 0; rr < 4; rr++)
                b1[(quad * 4 + rr) * SA + col] = (_Float16)fmaxf(acc[nn][rr] + bb, 0.f);
        }
    }

    // ---- fobs: h = e @ fobsW^T + b : b1 -> b0
    #pragma unroll 1
    for (int ch = 0; ch < 4; ch++) {
        zero4(acc);
        gemm_chunk4<8, USE_PREP>(Ab1, prep + FOBS_OFF + (ch * 4) * 512 + lane8, 16 * 512,
                                 fobsW + (size_t)(ch * 64 + l16) * HID + kq, HID, acc);
        #pragma unroll
        for (int nn = 0; nn < 4; nn++) {
            int col = ch * 64 + nn * 16 + l16;
            float bb = fobs_b[col];
            #pragma unroll
            for (int rr = 0; rr < 4; rr++)
                b0[(quad * 4 + rr) * SA + col] = (_Float16)(acc[nn][rr] + bb);
        }
    }

    // ---- GRU1 (x=0 => gi = b_ih). A = b0 (h). h1 -> b1; colsum -> Sp[wv]
    #pragma unroll 1
    for (int ch = 0; ch < 4; ch++) {
        float rg[4][4];
        zero4(acc);   // r-gate: ntg 0..15
        gemm_chunk4<8, USE_PREP>(Ab0, prep + WHH_OFF + (0 + ch * 4) * 512 + lane8, 48 * 512,
                                 whh + (size_t)((0 + ch * 4) * 16 + l16) * HID + kq, HID, acc);
        #pragma unroll
        for (int nn = 0; nn < 4; nn++) {
            int col = ch * 64 + nn * 16 + l16;
            float bb = b_ih[col] + b_hh[col];
            #pragma unroll
            for (int rr = 0; rr < 4; rr++)
                rg[nn][rr] = sigmoid_f(acc[nn][rr] + bb);
        }
        zero4(acc);   // n-gate: ntg 32..47
        gemm_chunk4<8, USE_PREP>(Ab0, prep + WHH_OFF + (32 + ch * 4) * 512 + lane8, 48 * 512,
                                 whh + (size_t)((32 + ch * 4) * 16 + l16) * HID + kq, HID, acc);
        #pragma unroll
        for (int nn = 0; nn < 4; nn++) {
            int col = ch * 64 + nn * 16 + l16;
            float bi = b_ih[512 + col], bh = b_hh[512 + col];
            #pragma unroll
            for (int rr = 0; rr < 4; rr++)
                rg[nn][rr] = tanh_f(bi + rg[nn][rr] * (acc[nn][rr] + bh));
        }
        zero4(acc);   // z-gate: ntg 16..31
        gemm_chunk4<8, USE_PREP>(Ab0, prep + WHH_OFF + (16 + ch * 4) * 512 + lane8, 48 * 512,
                                 whh + (size_t)((16 + ch * 4) * 16 + l16) * HID + kq, HID, acc);
        #pragma unroll
        for (int nn = 0; nn < 4; nn++) {
            int col = ch * 64 + nn * 16 + l16;
            float bb = b_ih[256 + col] + b_hh[256 + col];
            float s = 0.f;
            #pragma unroll
            for (int rr = 0; rr < 4; rr++) {
                int row = quad * 4 + rr;
                float z = sigmoid_f(acc[nn][rr] + bb);
                float hold = (float)b0[row * SA + col];
                float h1 = (1.f - z) * rg[nn][rr] + z * hold;
                b1[row * SA + col] = (_Float16)h1;
                s += h1;
            }
            s += __shfl_xor(s, 16);
            s += __shfl_xor(s, 32);
            if (quad == 0) Sp[wv][col] = s;   // 16-row partial colsum
        }
    }

    __syncthreads();   // the ONLY barrier: exchange Sp between the 2 waves

    // ---- comm: c = (Sp0 + Sp1 - h1)/32 : b1(h1) -> b0(c)
    #pragma unroll
    for (int it = 0; it < 8; it++) {
        int g = it * 64 + lane;               // half8 group, 512 total
        int row = g >> 5, cg = (g & 31) * 8;
        half8 hv = *(const half8*)(b1 + row * SA + cg);
        float4v s0 = *(const float4v*)(&Sp[0][cg]);
        float4v s1 = *(const float4v*)(&Sp[0][cg + 4]);
        float4v t0 = *(const float4v*)(&Sp[1][cg]);
        float4v t1 = *(const float4v*)(&Sp[1][cg + 4]);
        half8 cv;
        #pragma unroll
        for (int j = 0; j < 4; j++) {
            cv[j]     = (_Float16)((s0[j] + t0[j] - (float)hv[j])     * (1.f / 32.f));
            cv[4 + j] = (_Float16)((s1[j] + t1[j] - (float)hv[4 + j]) * (1.f / 32.f));
        }
        *(half8*)(b0 + row * SA + cg) = cv;
    }

    // ---- GRU2: gi = c(b0) @ W_ih, gh = h1(b1) @ W_hh; fused decoder dot
    float p[4] = {0.f, 0.f, 0.f, 0.f};
    #pragma unroll 1
    for (int ch = 0; ch < 4; ch++) {
        float rg[4][4], tg[4][4];
        zero4(acc);   // r-gate: chain gi_r + gh_r
        gemm_chunk4<8, USE_PREP>(Ab0, prep + WIH_OFF + (0 + ch * 4) * 512 + lane8, 48 * 512,
                                 wih + (size_t)((0 + ch * 4) * 16 + l16) * HID + kq, HID, acc);
        gemm_chunk4<8, USE_PREP>(Ab1, prep + WHH_OFF + (0 + ch * 4) * 512 + lane8, 48 * 512,
                                 whh + (size_t)((0 + ch * 4) * 16 + l16) * HID + kq, HID, acc);
        #pragma unroll
        for (int nn = 0; nn < 4; nn++) {
            int col = ch * 64 + nn * 16 + l16;
            float bb = b_ih[col] + b_hh[col];
            #pragma unroll
            for (int rr = 0; rr < 4; rr++)
                rg[nn][rr] = sigmoid_f(acc[nn][rr] + bb);
        }
        zero4(acc);   // gh_n
        gemm_chunk4<8, USE_PREP>(Ab1, prep + WHH_OFF + (32 + ch * 4) * 512 + lane8, 48 * 512,
                                 whh + (size_t)((32 + ch * 4) * 16 + l16) * HID + kq, HID, acc);
        #pragma unroll
        for (int nn = 0; nn < 4; nn++) {
            int col = ch * 64 + nn * 16 + l16;
            float bh = b_hh[512 + col];
            #pragma unroll
            for (int rr = 0; rr < 4; rr++)
                tg[nn][rr] = acc[nn][rr] + bh;
        }
        zero4(acc);   // gi_n
        gemm_chunk4<8, USE_PREP>(Ab0, prep + WIH_OFF + (32 + ch * 4) * 512 + lane8, 48 * 512,
                                 wih + (size_t)((32 + ch * 4) * 16 + l16) * HID + kq, HID, acc);
        #pragma unroll
        for (int nn = 0; nn < 4; nn++) {
            int col = ch * 64 + nn * 16 + l16;
            float bi = b_ih[512 + col];
            #pragma unroll
            for (int rr = 0; rr < 4; rr++)
                rg[nn][rr] = tanh_f(acc[nn][rr] + bi + rg[nn][rr] * tg[nn][rr]);
        }
        zero4(acc);   // z-gate: chain gi_z + gh_z
        gemm_chunk4<8, USE_PREP>(Ab0, prep + WIH_OFF + (16 + ch * 4) * 512 + lane8, 48 * 512,
                                 wih + (size_t)((16 + ch * 4) * 16 + l16) * HID + kq, HID, acc);
        gemm_chunk4<8, USE_PREP>(Ab1, prep + WHH_OFF + (16 + ch * 4) * 512 + lane8, 48 * 512,
                                 whh + (size_t)((16 + ch * 4) * 16 + l16) * HID + kq, HID, acc);
        #pragma unroll
        for (int nn = 0; nn < 4; nn++) {
            int col = ch * 64 + nn * 16 + l16;
            float bb = b_ih[256 + col] + b_hh[256 + col];
            float dwv = dec_W[col];
            #pragma unroll
            for (int rr = 0; rr < 4; rr++) {
                int row = quad * 4 + rr;
                float z = sigmoid_f(acc[nn][rr] + bb);
                float h1v = (float)b1[row * SA + col];
                float h2 = (1.f - z) * rg[nn][rr] + z * h1v;
                p[rr] += h2 * dwv;
            }
        }
    }

    // ---- decoder reduce over cols (l16) and store 16 rows
    #pragma unroll
    for (int m = 1; m <= 8; m <<= 1)
        #pragma unroll
        for (int rr = 0; rr < 4; rr++)
            p[rr] += __shfl_xor(p[rr], m);
    if (l16 == 0) {
        float db = dec_b[0];
        #pragma unroll
        for (int rr = 0; rr < 4; rr++)
            out[(size_t)b * NA + wv * 16 + quad * 4 + rr] = p[rr] + db;
    }
}

extern "C" void kernel_launch(void* const* d_in, const int* in_sizes, int n_in,
                              void* d_out, int out_size, void* d_ws, size_t ws_size,
                              hipStream_t stream) {
    const float* obs   = (const float*)d_in[0];
    // d_in[1] (act) unused by reference
    const float* encW  = (const float*)d_in[2];
    const float* encb  = (const float*)d_in[3];
    const float* fobsW = (const float*)d_in[4];
    const float* fobsb = (const float*)d_in[5];
    const float* wih   = (const float*)d_in[6];
    const float* bih   = (const float*)d_in[7];
    const float* whh   = (const float*)d_in[8];
    const float* bhh   = (const float*)d_in[9];
    const float* decW  = (const float*)d_in[10];
    const float* decb  = (const float*)d_in[11];
    float* out = (float*)d_out;

    _Float16* prep = (_Float16*)d_ws;
    if (ws_size >= (size_t)PREP_TOTAL * sizeof(_Float16)) {
        prep_weights<<<240, 256, 0, stream>>>(encW, fobsW, wih, whh, prep);
        commnet_fused<1><<<NB, 128, 0, stream>>>(obs, prep, encb, fobsb, bih, bhh,
                                                 decW, decb, out, encW, fobsW, wih, whh);
    } else {
        commnet_fused<0><<<NB, 128, 0, stream>>>(obs, prep, encb, fobsb, bih, bhh,
                                                 decW, decb, out, encW, fobsW, wih, whh);
    }
}

// Round 5
// 398.351 us; speedup vs baseline: 1.1285x; 1.0140x over previous
//
#include <hip/hip_runtime.h>
#include <hip/hip_fp16.h>

// CommNet critic forward. R5: 1 WG = 1 wave (64 thr) = 1 full batch (32 agents).
// M=32 (2 m-tiles) per wave -> each B-fragment load feeds 2 MFMAs (halves L2
// traffic vs R4). Cross-agent mean is wave-local (shfl colsum) -> zero real
// barriers. 2 LDS ping-pong tiles/wave, 4 WGs/CU, unroll-2 k-loops.

#define NB   2048
#define NA   32
#define DIN  128
#define HID  256
#define SA   264   // f16 row stride: banks spread evenly for b128 A-frag reads

typedef _Float16 half8   __attribute__((ext_vector_type(8)));
typedef _Float16 half4_t __attribute__((ext_vector_type(4)));
typedef float    float4v __attribute__((ext_vector_type(4)));

// f16 weight-fragment arena in d_ws (element offsets)
#define ENC_OFF    0
#define FOBS_OFF   32768
#define WIH_OFF    98304
#define WHH_OFF    294912
#define PREP_TOTAL 491520   // f16 elements -> 983040 bytes

// One wave per (matrix, ks, nt) fragment tile; coalesced f32x4 reads, half8 write.
// frag[((ks*NT + nt)*64 + lane)*8 + j] = W[nt*16 + lane%16][ks*32 + (lane/16)*8 + j]
__global__ __launch_bounds__(256) void prep_weights(
        const float* __restrict__ encW, const float* __restrict__ fobsW,
        const float* __restrict__ wih,  const float* __restrict__ whh,
        _Float16* __restrict__ prep) {
    int W = blockIdx.x * 4 + (threadIdx.x >> 6);   // wave id 0..959
    int lane = threadIdx.x & 63;
    const float* src; int K, NT, base, idx;
    if (W < 64)       { src = encW;  K = 128; NT = 16; base = ENC_OFF;  idx = W; }
    else if (W < 192) { src = fobsW; K = 256; NT = 16; base = FOBS_OFF; idx = W - 64; }
    else if (W < 576) { src = wih;   K = 256; NT = 48; base = WIH_OFF;  idx = W - 192; }
    else              { src = whh;   K = 256; NT = 48; base = WHH_OFF;  idx = W - 576; }
    int nt = idx % NT, ks = idx / NT;
    int l16 = lane & 15, q = lane >> 4;
    const float* s = src + (size_t)(nt * 16 + l16) * K + ks * 32 + q * 8;
    float4v f0 = *(const float4v*)s;
    float4v f1 = *(const float4v*)(s + 4);
    half8 h;
    h[0] = (_Float16)f0[0]; h[1] = (_Float16)f0[1]; h[2] = (_Float16)f0[2]; h[3] = (_Float16)f0[3];
    h[4] = (_Float16)f1[0]; h[5] = (_Float16)f1[1]; h[6] = (_Float16)f1[2]; h[7] = (_Float16)f1[3];
    *(half8*)(prep + base + (((size_t)(ks * NT + nt) * 64 + lane) << 3)) = h;
}

__device__ __forceinline__ float sigmoid_f(float x) {
    x = fminf(fmaxf(x, -30.f), 30.f);
    return 1.f / (1.f + __expf(-x));
}
__device__ __forceinline__ float tanh_f(float x) {
    x = fminf(fmaxf(x, -15.f), 15.f);
    float e = __expf(-2.f * x);
    return (1.f - e) / (1.f + e);
}
__device__ __forceinline__ void zero24(float4v a[2][4]) {
    float4v z = {0.f, 0.f, 0.f, 0.f};
    #pragma unroll
    for (int m = 0; m < 2; m++)
        #pragma unroll
        for (int n = 0; n < 4; n++) a[m][n] = z;
}

// One wave: 32 rows (2 m-tiles) x 64 cols (4 ntiles). Ab = buf + l16*SA + kq.
// Bp = prep + OFF + g0*512 + lane*8 ; ks stride = NT*512 ; nn stride = 512.
// rawp = W + (g0*16 + l16)*K + kq (fp32 fallback).
template<int KSTEPS, int USE_PREP>
__device__ __forceinline__ void gemm2x4(
        const _Float16* __restrict__ Ab,
        const _Float16* __restrict__ Bp, int ldbk,
        const float* __restrict__ rawp, int K,
        float4v acc[2][4])
{
    #pragma unroll 2
    for (int ks = 0; ks < KSTEPS; ks++) {
        half8 a0 = *(const half8*)(Ab + ks * 32);
        half8 a1 = *(const half8*)(Ab + 16 * SA + ks * 32);
        #pragma unroll
        for (int nn = 0; nn < 4; nn++) {
            half8 b;
            if (USE_PREP) {
                b = *(const half8*)(Bp + ks * ldbk + nn * 512);
            } else {
                #pragma unroll
                for (int j = 0; j < 8; j++)
                    b[j] = (_Float16)rawp[(size_t)nn * 16 * K + ks * 32 + j];
            }
            acc[0][nn] = __builtin_amdgcn_mfma_f32_16x16x32_f16(a0, b, acc[0][nn], 0, 0, 0);
            acc[1][nn] = __builtin_amdgcn_mfma_f32_16x16x32_f16(a1, b, acc[1][nn], 0, 0, 0);
        }
    }
}

template<int USE_PREP>
__global__ __launch_bounds__(64, 2) void commnet_fused(
    const float* __restrict__ obs, const _Float16* __restrict__ prep,
    const float* __restrict__ enc_b, const float* __restrict__ fobs_b,
    const float* __restrict__ b_ih, const float* __restrict__ b_hh,
    const float* __restrict__ dec_W, const float* __restrict__ dec_b,
    float* __restrict__ out,
    const float* __restrict__ encW, const float* __restrict__ fobsW,
    const float* __restrict__ wih, const float* __restrict__ whh)
{
    const int b     = blockIdx.x;
    const int lane  = threadIdx.x;       // 0..63, one wave per WG
    const int l16   = lane & 15;
    const int quad  = lane >> 4;
    const int kq    = quad << 3;
    const int lane8 = lane << 3;

    __shared__ __align__(16) _Float16 buf[2][NA * SA];  // ping-pong activation tiles
    __shared__ __align__(16) float Sarr[HID];           // colsums for comm

    _Float16* b0 = &buf[0][0];
    _Float16* b1 = &buf[1][0];
    const _Float16* Ab0 = b0 + l16 * SA + kq;
    const _Float16* Ab1 = b1 + l16 * SA + kq;

    // ---- stage obs 32x128 (fp32 -> f16 LDS b0)
    {
        const float* obsb = obs + (size_t)b * NA * DIN;
        #pragma unroll
        for (int it = 0; it < 16; it++) {
            int i = it * 64 + lane;           // float4 idx, 1024 total
            float4v v = ((const float4v*)obsb)[i];
            int row = i >> 5, c4 = (i & 31) * 4;
            half4_t hv;
            hv[0] = (_Float16)v[0]; hv[1] = (_Float16)v[1];
            hv[2] = (_Float16)v[2]; hv[3] = (_Float16)v[3];
            *(half4_t*)(b0 + row * SA + c4) = hv;
        }
    }
    __syncthreads();   // in-wave LDS fence (1 wave: ~free)

    float4v acc[2][4];

    // ---- encoder: e = relu(obs @ encW^T + b) : b0 -> b1   (K=128, NT=16)
    #pragma unroll 1
    for (int ch = 0; ch < 4; ch++) {
        zero24(acc);
        gemm2x4<4, USE_PREP>(Ab0, prep + ENC_OFF + (ch * 4) * 512 + lane8, 16 * 512,
                             encW + (size_t)((ch * 4) * 16 + l16) * DIN + kq, DIN, acc);
        #pragma unroll
        for (int nn = 0; nn < 4; nn++) {
            int col = ch * 64 + nn * 16 + l16;
            float bb = enc_b[col];
            #pragma unroll
            for (int mt = 0; mt < 2; mt++)
                #pragma unroll
                for (int rr = 0; rr < 4; rr++)
                    b1[(mt * 16 + quad * 4 + rr) * SA + col] =
                        (_Float16)fmaxf(acc[mt][nn][rr] + bb, 0.f);
        }
    }
    __syncthreads();

    // ---- fobs: h = e @ fobsW^T + b : b1 -> b0   (K=256, NT=16)
    #pragma unroll 1
    for (int ch = 0; ch < 4; ch++) {
        zero24(acc);
        gemm2x4<8, USE_PREP>(Ab1, prep + FOBS_OFF + (ch * 4) * 512 + lane8, 16 * 512,
                             fobsW + (size_t)((ch * 4) * 16 + l16) * HID + kq, HID, acc);
        #pragma unroll
        for (int nn = 0; nn < 4; nn++) {
            int col = ch * 64 + nn * 16 + l16;
            float bb = fobs_b[col];
            #pragma unroll
            for (int mt = 0; mt < 2; mt++)
                #pragma unroll
                for (int rr = 0; rr < 4; rr++)
                    b0[(mt * 16 + quad * 4 + rr) * SA + col] =
                        (_Float16)(acc[mt][nn][rr] + bb);
        }
    }
    __syncthreads();

    // ---- GRU1 (x=0 => gi = b_ih). A = b0 (h). h1 -> b1; colsums -> Sarr
    #pragma unroll 1
    for (int ch = 0; ch < 4; ch++) {
        float rg[2][4][4];
        zero24(acc);   // r-gate: nt 0..15
        gemm2x4<8, USE_PREP>(Ab0, prep + WHH_OFF + (0 + ch * 4) * 512 + lane8, 48 * 512,
                             whh + (size_t)((0 + ch * 4) * 16 + l16) * HID + kq, HID, acc);
        #pragma unroll
        for (int nn = 0; nn < 4; nn++) {
            int col = ch * 64 + nn * 16 + l16;
            float bb = b_ih[col] + b_hh[col];
            #pragma unroll
            for (int mt = 0; mt < 2; mt++)
                #pragma unroll
                for (int rr = 0; rr < 4; rr++)
                    rg[mt][nn][rr] = sigmoid_f(acc[mt][nn][rr] + bb);
        }
        zero24(acc);   // n-gate: nt 32..47
        gemm2x4<8, USE_PREP>(Ab0, prep + WHH_OFF + (32 + ch * 4) * 512 + lane8, 48 * 512,
                             whh + (size_t)((32 + ch * 4) * 16 + l16) * HID + kq, HID, acc);
        #pragma unroll
        for (int nn = 0; nn < 4; nn++) {
            int col = ch * 64 + nn * 16 + l16;
            float bi = b_ih[512 + col], bh = b_hh[512 + col];
            #pragma unroll
            for (int mt = 0; mt < 2; mt++)
                #pragma unroll
                for (int rr = 0; rr < 4; rr++)
                    rg[mt][nn][rr] = tanh_f(bi + rg[mt][nn][rr] * (acc[mt][nn][rr] + bh));
        }
        zero24(acc);   // z-gate: nt 16..31
        gemm2x4<8, USE_PREP>(Ab0, prep + WHH_OFF + (16 + ch * 4) * 512 + lane8, 48 * 512,
                             whh + (size_t)((16 + ch * 4) * 16 + l16) * HID + kq, HID, acc);
        #pragma unroll
        for (int nn = 0; nn < 4; nn++) {
            int col = ch * 64 + nn * 16 + l16;
            float bb = b_ih[256 + col] + b_hh[256 + col];
            float s = 0.f;
            #pragma unroll
            for (int mt = 0; mt < 2; mt++)
                #pragma unroll
                for (int rr = 0; rr < 4; rr++) {
                    int row = mt * 16 + quad * 4 + rr;
                    float z = sigmoid_f(acc[mt][nn][rr] + bb);
                    float hold = (float)b0[row * SA + col];
                    float h1 = (1.f - z) * rg[mt][nn][rr] + z * hold;
                    b1[row * SA + col] = (_Float16)h1;
                    s += h1;
                }
            s += __shfl_xor(s, 16);        // full 32-row colsum (sum over quads)
            s += __shfl_xor(s, 32);
            if (lane < 16) Sarr[(ch * 4 + nn) * 16 + lane] = s;
        }
    }
    __syncthreads();

    // ---- comm: c = (Sarr - h1)/32 : b1 -> b0 (h dead)
    #pragma unroll
    for (int it = 0; it < 16; it++) {
        int g = it * 64 + lane;               // half8 group, 1024 total
        int row = g >> 5, cg = (g & 31) * 8;
        half8 hv = *(const half8*)(b1 + row * SA + cg);
        float4v s0 = *(const float4v*)(&Sarr[cg]);
        float4v s1 = *(const float4v*)(&Sarr[cg + 4]);
        half8 cv;
        #pragma unroll
        for (int j = 0; j < 4; j++) {
            cv[j]     = (_Float16)((s0[j] - (float)hv[j])     * (1.f / 32.f));
            cv[4 + j] = (_Float16)((s1[j] - (float)hv[4 + j]) * (1.f / 32.f));
        }
        *(half8*)(b0 + row * SA + cg) = cv;
    }
    __syncthreads();

    // ---- GRU2: gi = c(b0) @ W_ih, gh = h1(b1) @ W_hh; fused decoder dot
    float p[2][4] = {};
    #pragma unroll 1
    for (int ch = 0; ch < 4; ch++) {
        float rg[2][4][4], tg[2][4][4];
        zero24(acc);   // r-gate: chain gi_r + gh_r
        gemm2x4<8, USE_PREP>(Ab0, prep + WIH_OFF + (0 + ch * 4) * 512 + lane8, 48 * 512,
                             wih + (size_t)((0 + ch * 4) * 16 + l16) * HID + kq, HID, acc);
        gemm2x4<8, USE_PREP>(Ab1, prep + WHH_OFF + (0 + ch * 4) * 512 + lane8, 48 * 512,
                             whh + (size_t)((0 + ch * 4) * 16 + l16) * HID + kq, HID, acc);
        #pragma unroll
        for (int nn = 0; nn < 4; nn++) {
            int col = ch * 64 + nn * 16 + l16;
            float bb = b_ih[col] + b_hh[col];
            #pragma unroll
            for (int mt = 0; mt < 2; mt++)
                #pragma unroll
                for (int rr = 0; rr < 4; rr++)
                    rg[mt][nn][rr] = sigmoid_f(acc[mt][nn][rr] + bb);
        }
        zero24(acc);   // gh_n
        gemm2x4<8, USE_PREP>(Ab1, prep + WHH_OFF + (32 + ch * 4) * 512 + lane8, 48 * 512,
                             whh + (size_t)((32 + ch * 4) * 16 + l16) * HID + kq, HID, acc);
        #pragma unroll
        for (int nn = 0; nn < 4; nn++) {
            int col = ch * 64 + nn * 16 + l16;
            float bh = b_hh[512 + col];
            #pragma unroll
            for (int mt = 0; mt < 2; mt++)
                #pragma unroll
                for (int rr = 0; rr < 4; rr++)
                    tg[mt][nn][rr] = acc[mt][nn][rr] + bh;
        }
        zero24(acc);   // gi_n
        gemm2x4<8, USE_PREP>(Ab0, prep + WIH_OFF + (32 + ch * 4) * 512 + lane8, 48 * 512,
                             wih + (size_t)((32 + ch * 4) * 16 + l16) * HID + kq, HID, acc);
        #pragma unroll
        for (int nn = 0; nn < 4; nn++) {
            int col = ch * 64 + nn * 16 + l16;
            float bi = b_ih[512 + col];
            #pragma unroll
            for (int mt = 0; mt < 2; mt++)
                #pragma unroll
                for (int rr = 0; rr < 4; rr++)
                    rg[mt][nn][rr] = tanh_f(acc[mt][nn][rr] + bi
                                            + rg[mt][nn][rr] * tg[mt][nn][rr]);
        }
        zero24(acc);   // z-gate: chain gi_z + gh_z
        gemm2x4<8, USE_PREP>(Ab0, prep + WIH_OFF + (16 + ch * 4) * 512 + lane8, 48 * 512,
                             wih + (size_t)((16 + ch * 4) * 16 + l16) * HID + kq, HID, acc);
        gemm2x4<8, USE_PREP>(Ab1, prep + WHH_OFF + (16 + ch * 4) * 512 + lane8, 48 * 512,
                             whh + (size_t)((16 + ch * 4) * 16 + l16) * HID + kq, HID, acc);
        #pragma unroll
        for (int nn = 0; nn < 4; nn++) {
            int col = ch * 64 + nn * 16 + l16;
            float bb = b_ih[256 + col] + b_hh[256 + col];
            float dwv = dec_W[col];
            #pragma unroll
            for (int mt = 0; mt < 2; mt++)
                #pragma unroll
                for (int rr = 0; rr < 4; rr++) {
                    int row = mt * 16 + quad * 4 + rr;
                    float z = sigmoid_f(acc[mt][nn][rr] + bb);
                    float h1v = (float)b1[row * SA + col];
                    float h2 = (1.f - z) * rg[mt][nn][rr] + z * h1v;
                    p[mt][rr] += h2 * dwv;
                }
        }
    }

    // ---- decoder reduce over cols (l16) and store 32 rows
    #pragma unroll
    for (int m = 1; m <= 8; m <<= 1)
        #pragma unroll
        for (int mt = 0; mt < 2; mt++)
            #pragma unroll
            for (int rr = 0; rr < 4; rr++)
                p[mt][rr] += __shfl_xor(p[mt][rr], m);
    if (l16 == 0) {
        float db = dec_b[0];
        #pragma unroll
        for (int mt = 0; mt < 2; mt++)
            #pragma unroll
            for (int rr = 0; rr < 4; rr++)
                out[(size_t)b * NA + mt * 16 + quad * 4 + rr] = p[mt][rr] + db;
    }
}

extern "C" void kernel_launch(void* const* d_in, const int* in_sizes, int n_in,
                              void* d_out, int out_size, void* d_ws, size_t ws_size,
                              hipStream_t stream) {
    const float* obs   = (const float*)d_in[0];
    // d_in[1] (act) unused by reference
    const float* encW  = (const float*)d_in[2];
    const float* encb  = (const float*)d_in[3];
    const float* fobsW = (const float*)d_in[4];
    const float* fobsb = (const float*)d_in[5];
    const float* wih   = (const float*)d_in[6];
    const float* bih   = (const float*)d_in[7];
    const float* whh   = (const float*)d_in[8];
    const float* bhh   = (const float*)d_in[9];
    const float* decW  = (const float*)d_in[10];
    const float* decb  = (const float*)d_in[11];
    float* out = (float*)d_out;

    _Float16* prep = (_Float16*)d_ws;
    if (ws_size >= (size_t)PREP_TOTAL * sizeof(_Float16)) {
        prep_weights<<<240, 256, 0, stream>>>(encW, fobsW, wih, whh, prep);
        commnet_fused<1><<<NB, 64, 0, stream>>>(obs, prep, encb, fobsb, bih, bhh,
                                                decW, decb, out, encW, fobsW, wih, whh);
    } else {
        commnet_fused<0><<<NB, 64, 0, stream>>>(obs, prep, encb, fobsb, bih, bhh,
                                                decW, decb, out, encW, fobsW, wih, whh);
    }
}